// Round 13
// baseline (217.200 us; speedup 1.0000x reference)
//
#include <hip/hip_runtime.h>
#include <hip/hip_bf16.h>
#include <math.h>

#define NH_ 4
#define S_  49
#define B_  16
#define H_  112
#define W_  112
#define WT  16

typedef __attribute__((ext_vector_type(8))) short short8;
typedef __attribute__((ext_vector_type(4))) float f32x4;

__device__ __forceinline__ unsigned short f2bf(float f) {
  union { __hip_bfloat16 h; unsigned short u; } c;
  c.h = __float2bfloat16(f);
  return c.u;
}
__device__ __forceinline__ short8 cvt8(float4 a, float4 b) {
  union { short8 s; unsigned short u[8]; } r;
  r.u[0] = f2bf(a.x); r.u[1] = f2bf(a.y); r.u[2] = f2bf(a.z); r.u[3] = f2bf(a.w);
  r.u[4] = f2bf(b.x); r.u[5] = f2bf(b.y); r.u[6] = f2bf(b.z); r.u[7] = f2bf(b.w);
  return r.s;
}

// ---- prep: Wqk f32 [256][128] -> bf16 in workspace (first 64 KB of ws ONLY —
//      reads past d_ws+65536 proved unreliable in rounds 5-7)
__global__ void wprep(const float* __restrict__ Wqk, unsigned short* __restrict__ Wb) {
  int i = (blockIdx.x * blockDim.x + threadIdx.x) * 4;
  float4 w = *(const float4*)(Wqk + i);
  ushort4 o; o.x = f2bf(w.x); o.y = f2bf(w.y); o.z = f2bf(w.z); o.w = f2bf(w.w);
  *(ushort4*)(Wb + i) = o;
}

// LDS map (bytes) — unchanged from round 9:
//   0     : qk planes, 8 x 4112 = 32896 (plane = head*2+s; [64 rows][32 e] bf16, 16B skew)
//           outb f32 [49][132] = 25872 aliases after the PV barrier
//   32896 : Vt_p bf16 4 x [32 e][72 slots] = 18432 (k-permuted pixel slots, p>=49 zeroed)
//   51328 : posl f32 [169] = 676      -> total 52004 -> 3 blocks/CU
#define PSTR   4112
#define SM_VT  32896
#define SM_POS 51328
#define SM_TOT 52004

__global__ __launch_bounds__(256, 3) void swin_fused(
    const float* __restrict__ x, const float* __restrict__ v,
    const float* __restrict__ bqk, const float* __restrict__ pos,
    const unsigned short* __restrict__ Wb, float* __restrict__ out)
{
  __shared__ __align__(16) char smem[SM_TOT];
  float* posl = (float*)(smem + SM_POS);

  const int tid  = threadIdx.x;
  const int lane = tid & 63;
  const int g    = lane >> 4, l15 = lane & 15;
  const int wv   = tid >> 6;
  const int blk  = blockIdx.x;
  const int ww   = blk % WT, wh = (blk / WT) % WT, b = blk / (WT * WT);

  if (tid < 169) posl[tid] = pos[tid];

  // ---- Vt_p build: pixel t stored at permuted k-slot so PV B-frag is register-local.
  //   t = 16b1b0 + 4gg + rr -> k = 32b1 + 8gg + 4b0 + rr (bijective on 0..63)
  #pragma unroll
  for (int it = 0; it < 2; ++it) {
    const int idx = tid + it * 256;          // 0..511
    const int e = idx & 31, p4 = idx >> 5;   // e: channel-quad, p4: pixel quad 0..15
    const int kbase = 32 * (p4 >> 3) + 8 * (p4 & 3) + 4 * ((p4 >> 2) & 1);
    union { ushort4 v4; unsigned short u[4]; } hv[4];
    #pragma unroll
    for (int j = 0; j < 4; ++j) {
      const int p = p4 * 4 + j;
      float4 vv = {0.f, 0.f, 0.f, 0.f};
      if (p < S_) {
        const int px = p / 7, py = p % 7;
        const int gi = (wh * 7 + px + 4) % H_;
        const int gj = (ww * 7 + py + 4) % W_;
        vv = ((const float4*)(v + (((size_t)b * H_ + gi) * W_ + gj) * 128))[e];
      }
      hv[0].u[j] = f2bf(vv.x); hv[1].u[j] = f2bf(vv.y);
      hv[2].u[j] = f2bf(vv.z); hv[3].u[j] = f2bf(vv.w);
    }
    #pragma unroll
    for (int h = 0; h < 4; ++h)
      *(ushort4*)(smem + SM_VT + h * 4608 + e * 144 + kbase * 2) = hv[h].v4;
  }

  // ---- projection: A-frags from global; kk-outer with acc[16] and 4-wide
  //      independent Wb-load batches (ILP), NO setprio (r12 disambiguation).
  {
    const int prow = 16 * wv + l15;
    const int pc = prow < S_ ? prow : S_ - 1;   // clamp; rows >=49 discarded later
    const int px = pc / 7, py = pc % 7;
    const int gi = (wh * 7 + px + 4) % H_;
    const int gj = (ww * 7 + py + 4) % W_;
    const float* xrow = x + (((size_t)b * H_ + gi) * W_ + gj) * 128;
    short8 af[4];
    #pragma unroll
    for (int kk = 0; kk < 4; ++kk) {
      float4 a0 = *(const float4*)(xrow + kk * 32 + g * 8);
      float4 a1 = *(const float4*)(xrow + kk * 32 + g * 8 + 4);
      af[kk] = cvt8(a0, a1);
    }
    f32x4 acc[16];
    #pragma unroll
    for (int i = 0; i < 16; ++i) acc[i] = (f32x4){0.f, 0.f, 0.f, 0.f};
    #pragma unroll
    for (int kk = 0; kk < 4; ++kk) {
      #pragma unroll
      for (int c = 0; c < 4; ++c) {          // 4 batches of 4 independent loads
        short8 bfr[4];
        #pragma unroll
        for (int u = 0; u < 4; ++u) {
          const int n = (c * 4 + u) * 16 + l15;
          bfr[u] = *(const short8*)(Wb + n * 128 + kk * 32 + g * 8);
        }
        #pragma unroll
        for (int u = 0; u < 4; ++u)
          acc[c * 4 + u] = __builtin_amdgcn_mfma_f32_16x16x32_bf16(af[kk], bfr[u], acc[c * 4 + u], 0, 0, 0);
      }
    }
    const int mbase = 16 * wv + 4 * g;
    #pragma unroll
    for (int n16 = 0; n16 < 16; ++n16) {
      const int n = n16 * 16 + l15;
      const float bias = bqk[n];
      char* plane = smem + ((((n >> 1) & 3) * 2 + (n & 1))) * PSTR;   // 2h+s
      const int eoff = (n >> 3) * 2;
      #pragma unroll
      for (int r = 0; r < 4; ++r)
        if (mbase + r < S_)                  // skip garbage rows: -23% conflicted writes
          *(unsigned short*)(plane + (mbase + r) * 64 + eoff) = f2bf(acc[n16][r] + bias);
    }
  }
  __syncthreads();   // qk planes + Vt + posl ready

  // ---- attention: wave = head; SWAPPED QK^T -> lane-local P columns
  const bool maskR = (wh == WT - 1), maskC = (ww == WT - 1);
  const char* qpl = smem + (wv * 2 + 0) * PSTR;
  const char* kpl = smem + (wv * 2 + 1) * PSTR;
  short8 qf[4], kf[4];
  #pragma unroll
  for (int t4 = 0; t4 < 4; ++t4) {
    qf[t4] = *(const short8*)(qpl + (16 * t4 + l15) * 64 + g * 16);
    kf[t4] = *(const short8*)(kpl + (16 * t4 + l15) * 64 + g * 16);
  }

  // st[nt][mt]: D[row = t = 16nt+4g+r][col = m = 16mt+l15]
  f32x4 st[4][4];
  #pragma unroll
  for (int nt = 0; nt < 4; ++nt)
    #pragma unroll
    for (int mt = 0; mt < 4; ++mt) {
      f32x4 z = {0.f, 0.f, 0.f, 0.f};
      st[nt][mt] = __builtin_amdgcn_mfma_f32_16x16x32_bf16(kf[nt], qf[mt], z, 0, 0, 0);
    }

  // t-geometry per (nt, r): t = 16nt + 4g + r
  int tix[4][4]; bool txg[4][4], tyg[4][4], tvl[4][4];
  #pragma unroll
  for (int nt = 0; nt < 4; ++nt)
    #pragma unroll
    for (int r = 0; r < 4; ++r) {
      const int t = 16 * nt + 4 * g + r;
      const int tx = t / 7, ty = t - 7 * tx;
      tix[nt][r] = tx * 13 + ty;
      txg[nt][r] = (tx >= 4); tyg[nt][r] = (ty >= 4);
      tvl[nt][r] = (t < S_);
    }

  if (maskR || maskC) {      // uniform branch: ~12% of blocks
    #pragma unroll
    for (int mt = 0; mt < 4; ++mt) {
      const int m = 16 * mt + l15;
      const int mc = m < S_ ? m : S_ - 1;
      const int px = mc / 7, py = mc - 7 * px;
      const bool pxg = (px >= 4), pyg = (py >= 4);
      #pragma unroll
      for (int nt = 0; nt < 4; ++nt)
        #pragma unroll
        for (int r = 0; r < 4; ++r) {
          if ((maskR && (pxg != txg[nt][r])) || (maskC && (pyg != tyg[nt][r])))
            st[nt][mt][r] = -INFINITY;
        }
    }
  }

  // scale + bias + exp -> pack P^T fragments (register-local; k-order matches Vt_p)
  const float scale = 0.17677669529663687f;   // 1/sqrt(32)
  short8 pvb[4][2];   // [mt][ks]; elem j = j2*4+r <-> t = 16(2ks+j2)+4g+r
  #pragma unroll
  for (int mt = 0; mt < 4; ++mt) {
    const int m = 16 * mt + l15;
    const int mc = m < S_ ? m : S_ - 1;
    const int px = mc / 7, py = mc - 7 * px;
    const int pofs = 84 - px * 13 - py;
    union { short8 s8; unsigned short h[8]; } pk[2];
    #pragma unroll
    for (int nt = 0; nt < 4; ++nt)
      #pragma unroll
      for (int r = 0; r < 4; ++r) {
        float s = st[nt][mt][r] * scale + posl[tix[nt][r] + pofs];
        float e = tvl[nt][r] ? __expf(s) : 0.f;
        pk[nt >> 1].h[(nt & 1) * 4 + r] = f2bf(e);
      }
    pvb[mt][0] = pk[0].s8;
    pvb[mt][1] = pk[1].s8;
  }

  // PV: O^T = V^T . P^T ; denominators via ones-operand MFMA
  f32x4 o_[2][4], d_[4];
  #pragma unroll
  for (int mt = 0; mt < 4; ++mt) {
    o_[0][mt] = (f32x4){0.f, 0.f, 0.f, 0.f};
    o_[1][mt] = (f32x4){0.f, 0.f, 0.f, 0.f};
    d_[mt]    = (f32x4){0.f, 0.f, 0.f, 0.f};
  }
  {
    const char* Vb = smem + SM_VT + wv * 4608;
    union { short8 s8; unsigned short h[8]; } one;
    #pragma unroll
    for (int j = 0; j < 8; ++j) one.h[j] = 0x3F80;   // bf16 1.0
    #pragma unroll
    for (int ks = 0; ks < 2; ++ks) {
      short8 va[2];
      #pragma unroll
      for (int et = 0; et < 2; ++et)
        va[et] = *(const short8*)(Vb + (16 * et + l15) * 144 + ks * 64 + g * 16);
      #pragma unroll
      for (int mt = 0; mt < 4; ++mt) {
        o_[0][mt] = __builtin_amdgcn_mfma_f32_16x16x32_bf16(va[0], pvb[mt][ks], o_[0][mt], 0, 0, 0);
        o_[1][mt] = __builtin_amdgcn_mfma_f32_16x16x32_bf16(va[1], pvb[mt][ks], o_[1][mt], 0, 0, 0);
        d_[mt]    = __builtin_amdgcn_mfma_f32_16x16x32_bf16(one.s8, pvb[mt][ks], d_[mt], 0, 0, 0);
      }
    }
  }
  __syncthreads();   // all waves done reading planes/Vt -> region becomes outb

  // O^T tile: row e = 16et+4g+r, col m = 16mt+l15; d rows all identical
  float (*outb)[132] = (float (*)[132])smem;
  #pragma unroll
  for (int mt = 0; mt < 4; ++mt) {
    const int m = 16 * mt + l15;
    if (m < S_) {
      const float inv = 1.f / d_[mt][0];
      #pragma unroll
      for (int et = 0; et < 2; ++et)
        #pragma unroll
        for (int r = 0; r < 4; ++r)
          outb[m][(16 * et + 4 * g + r) * 4 + wv] = o_[et][mt][r] * inv;
    }
  }
  __syncthreads();

  // ---- coalesced output with un-roll(+3)
  for (int idx = tid; idx < S_ * 32; idx += 256) {
    const int pp = idx >> 5, c4 = idx & 31;
    const int ppx = pp / 7, ppy = pp % 7;
    const int fi = (wh * 7 + ppx + 3) % H_;
    const int fj = (ww * 7 + ppy + 3) % W_;
    float4 val = *(const float4*)&outb[pp][c4 * 4];
    ((float4*)(out + (((size_t)b * H_ + fi) * W_ + fj) * 128))[c4] = val;
  }
}

extern "C" void kernel_launch(void* const* d_in, const int* in_sizes, int n_in,
                              void* d_out, int out_size, void* d_ws, size_t ws_size,
                              hipStream_t stream) {
  const float* x   = (const float*)d_in[0];
  const float* v   = (const float*)d_in[1];
  const float* Wqk = (const float*)d_in[2];
  const float* bqk = (const float*)d_in[3];
  const float* pos = (const float*)d_in[4];
  float* out = (float*)d_out;
  unsigned short* Wb = (unsigned short*)d_ws;   // 65536 B (do NOT use ws beyond this)

  hipLaunchKernelGGL(wprep, dim3(32), dim3(256), 0, stream, Wqk, Wb);
  hipLaunchKernelGGL(swin_fused, dim3(B_ * WT * WT), dim3(256), 0, stream,
                     x, v, bqk, pos, Wb, out);
}

// Round 14
// 165.814 us; speedup vs baseline: 1.3099x; 1.3099x over previous
//
#include <hip/hip_runtime.h>
#include <hip/hip_bf16.h>
#include <math.h>

#define NH_ 4
#define S_  49
#define B_  16
#define H_  112
#define W_  112
#define WT  16

typedef __attribute__((ext_vector_type(8))) short short8;
typedef __attribute__((ext_vector_type(4))) float f32x4;

__device__ __forceinline__ unsigned short f2bf(float f) {
  union { __hip_bfloat16 h; unsigned short u; } c;
  c.h = __float2bfloat16(f);
  return c.u;
}
__device__ __forceinline__ short8 cvt8(float4 a, float4 b) {
  union { short8 s; unsigned short u[8]; } r;
  r.u[0] = f2bf(a.x); r.u[1] = f2bf(a.y); r.u[2] = f2bf(a.z); r.u[3] = f2bf(a.w);
  r.u[4] = f2bf(b.x); r.u[5] = f2bf(b.y); r.u[6] = f2bf(b.z); r.u[7] = f2bf(b.w);
  return r.s;
}

// ---- prep: Wqk f32 [256][128] -> bf16 in workspace (first 64 KB of ws ONLY —
//      reads past d_ws+65536 proved unreliable in rounds 5-7)
__global__ void wprep(const float* __restrict__ Wqk, unsigned short* __restrict__ Wb) {
  int i = (blockIdx.x * blockDim.x + threadIdx.x) * 4;
  float4 w = *(const float4*)(Wqk + i);
  ushort4 o; o.x = f2bf(w.x); o.y = f2bf(w.y); o.z = f2bf(w.z); o.w = f2bf(w.w);
  *(ushort4*)(Wb + i) = o;
}

// LDS map (bytes) — unchanged from round 9:
//   0     : qk planes, 8 x 4112 = 32896 (plane = head*2+s; [64 rows][32 e] bf16, 16B skew)
//           outb f32 [49][132] = 25872 aliases after the PV barrier
//   32896 : Vt_p bf16 4 x [32 e][72 slots] = 18432 (k-permuted pixel slots, p>=49 zeroed)
//   51328 : posl f32 [169] = 676      -> total 52004 -> 3 blocks/CU
#define PSTR   4112
#define SM_VT  32896
#define SM_POS 51328
#define SM_TOT 52004

__global__ __launch_bounds__(256, 3) void swin_fused(
    const float* __restrict__ x, const float* __restrict__ v,
    const float* __restrict__ bqk, const float* __restrict__ pos,
    const unsigned short* __restrict__ Wb, float* __restrict__ out)
{
  __shared__ __align__(16) char smem[SM_TOT];
  float* posl = (float*)(smem + SM_POS);

  const int tid  = threadIdx.x;
  const int lane = tid & 63;
  const int g    = lane >> 4, l15 = lane & 15;
  const int wv   = tid >> 6;
  const int blk  = blockIdx.x;
  const int ww   = blk % WT, wh = (blk / WT) % WT, b = blk / (WT * WT);

  if (tid < 169) posl[tid] = pos[tid];

  // ---- Vt_p build: pixel t stored at permuted k-slot so PV B-frag is register-local.
  //   t = 16b1b0 + 4gg + rr -> k = 32b1 + 8gg + 4b0 + rr (bijective on 0..63)
  #pragma unroll
  for (int it = 0; it < 2; ++it) {
    const int idx = tid + it * 256;          // 0..511
    const int e = idx & 31, p4 = idx >> 5;   // e: channel-quad, p4: pixel quad 0..15
    const int kbase = 32 * (p4 >> 3) + 8 * (p4 & 3) + 4 * ((p4 >> 2) & 1);
    union { ushort4 v4; unsigned short u[4]; } hv[4];
    #pragma unroll
    for (int j = 0; j < 4; ++j) {
      const int p = p4 * 4 + j;
      float4 vv = {0.f, 0.f, 0.f, 0.f};
      if (p < S_) {
        const int px = p / 7, py = p % 7;
        const int gi = (wh * 7 + px + 4) % H_;
        const int gj = (ww * 7 + py + 4) % W_;
        vv = ((const float4*)(v + (((size_t)b * H_ + gi) * W_ + gj) * 128))[e];
      }
      hv[0].u[j] = f2bf(vv.x); hv[1].u[j] = f2bf(vv.y);
      hv[2].u[j] = f2bf(vv.z); hv[3].u[j] = f2bf(vv.w);
    }
    #pragma unroll
    for (int h = 0; h < 4; ++h)
      *(ushort4*)(smem + SM_VT + h * 4608 + e * 144 + kbase * 2) = hv[h].v4;
  }

  // ---- projection: quarter-tiled for L1 reuse of Wb.
  //   q-outer: 64 n-rows x 256 B = 16 KB working set (fits 32 KB L1, shared by the
  //   4 barrier-aligned waves). acc[4] only (16 VGPR) — avoids the r13 spill cliff.
  {
    const int prow = 16 * wv + l15;
    const int pc = prow < S_ ? prow : S_ - 1;   // clamp; rows >=49 discarded later
    const int px = pc / 7, py = pc % 7;
    const int gi = (wh * 7 + px + 4) % H_;
    const int gj = (ww * 7 + py + 4) % W_;
    const float* xrow = x + (((size_t)b * H_ + gi) * W_ + gj) * 128;
    short8 af[4];
    #pragma unroll
    for (int kk = 0; kk < 4; ++kk) {
      float4 a0 = *(const float4*)(xrow + kk * 32 + g * 8);
      float4 a1 = *(const float4*)(xrow + kk * 32 + g * 8 + 4);
      af[kk] = cvt8(a0, a1);
    }
    const int mbase = 16 * wv + 4 * g;
    #pragma unroll
    for (int q = 0; q < 4; ++q) {
      f32x4 acc[4];
      #pragma unroll
      for (int u = 0; u < 4; ++u) acc[u] = (f32x4){0.f, 0.f, 0.f, 0.f};
      #pragma unroll
      for (int kk = 0; kk < 4; ++kk) {
        #pragma unroll
        for (int u = 0; u < 4; ++u) {
          const int n = (q * 4 + u) * 16 + l15;
          short8 bfr = *(const short8*)(Wb + n * 128 + kk * 32 + g * 8);
          acc[u] = __builtin_amdgcn_mfma_f32_16x16x32_bf16(af[kk], bfr, acc[u], 0, 0, 0);
        }
      }
      #pragma unroll
      for (int u = 0; u < 4; ++u) {
        const int n = (q * 4 + u) * 16 + l15;
        const float bias = bqk[n];
        char* plane = smem + ((((n >> 1) & 3) * 2 + (n & 1))) * PSTR;   // 2h+s
        const int eoff = (n >> 3) * 2;
        #pragma unroll
        for (int r = 0; r < 4; ++r)
          *(unsigned short*)(plane + (mbase + r) * 64 + eoff) = f2bf(acc[u][r] + bias);
      }
    }
  }
  __syncthreads();   // qk planes + Vt + posl ready

  // ---- attention: wave = head; SWAPPED QK^T -> lane-local P columns
  const bool maskR = (wh == WT - 1), maskC = (ww == WT - 1);
  const char* qpl = smem + (wv * 2 + 0) * PSTR;
  const char* kpl = smem + (wv * 2 + 1) * PSTR;
  short8 qf[4], kf[4];
  #pragma unroll
  for (int t4 = 0; t4 < 4; ++t4) {
    qf[t4] = *(const short8*)(qpl + (16 * t4 + l15) * 64 + g * 16);
    kf[t4] = *(const short8*)(kpl + (16 * t4 + l15) * 64 + g * 16);
  }

  // st[nt][mt]: D[row = t = 16nt+4g+r][col = m = 16mt+l15]
  f32x4 st[4][4];
  #pragma unroll
  for (int nt = 0; nt < 4; ++nt)
    #pragma unroll
    for (int mt = 0; mt < 4; ++mt) {
      f32x4 z = {0.f, 0.f, 0.f, 0.f};
      st[nt][mt] = __builtin_amdgcn_mfma_f32_16x16x32_bf16(kf[nt], qf[mt], z, 0, 0, 0);
    }

  // t-geometry per (nt, r): t = 16nt + 4g + r
  int tix[4][4]; bool txg[4][4], tyg[4][4], tvl[4][4];
  #pragma unroll
  for (int nt = 0; nt < 4; ++nt)
    #pragma unroll
    for (int r = 0; r < 4; ++r) {
      const int t = 16 * nt + 4 * g + r;
      const int tx = t / 7, ty = t - 7 * tx;
      tix[nt][r] = tx * 13 + ty;
      txg[nt][r] = (tx >= 4); tyg[nt][r] = (ty >= 4);
      tvl[nt][r] = (t < S_);
    }

  if (maskR || maskC) {      // uniform branch: ~12% of blocks
    #pragma unroll
    for (int mt = 0; mt < 4; ++mt) {
      const int m = 16 * mt + l15;
      const int mc = m < S_ ? m : S_ - 1;
      const int px = mc / 7, py = mc - 7 * px;
      const bool pxg = (px >= 4), pyg = (py >= 4);
      #pragma unroll
      for (int nt = 0; nt < 4; ++nt)
        #pragma unroll
        for (int r = 0; r < 4; ++r) {
          if ((maskR && (pxg != txg[nt][r])) || (maskC && (pyg != tyg[nt][r])))
            st[nt][mt][r] = -INFINITY;
        }
    }
  }

  // scale + bias + exp -> pack P^T fragments (register-local; k-order matches Vt_p)
  const float scale = 0.17677669529663687f;   // 1/sqrt(32)
  short8 pvb[4][2];   // [mt][ks]; elem j = j2*4+r <-> t = 16(2ks+j2)+4g+r
  #pragma unroll
  for (int mt = 0; mt < 4; ++mt) {
    const int m = 16 * mt + l15;
    const int mc = m < S_ ? m : S_ - 1;
    const int px = mc / 7, py = mc - 7 * px;
    const int pofs = 84 - px * 13 - py;
    union { short8 s8; unsigned short h[8]; } pk[2];
    #pragma unroll
    for (int nt = 0; nt < 4; ++nt)
      #pragma unroll
      for (int r = 0; r < 4; ++r) {
        float s = st[nt][mt][r] * scale + posl[tix[nt][r] + pofs];
        float e = tvl[nt][r] ? __expf(s) : 0.f;
        pk[nt >> 1].h[(nt & 1) * 4 + r] = f2bf(e);
      }
    pvb[mt][0] = pk[0].s8;
    pvb[mt][1] = pk[1].s8;
  }

  // PV: O^T = V^T . P^T ; denominators via ones-operand MFMA
  f32x4 o_[2][4], d_[4];
  #pragma unroll
  for (int mt = 0; mt < 4; ++mt) {
    o_[0][mt] = (f32x4){0.f, 0.f, 0.f, 0.f};
    o_[1][mt] = (f32x4){0.f, 0.f, 0.f, 0.f};
    d_[mt]    = (f32x4){0.f, 0.f, 0.f, 0.f};
  }
  {
    const char* Vb = smem + SM_VT + wv * 4608;
    union { short8 s8; unsigned short h[8]; } one;
    #pragma unroll
    for (int j = 0; j < 8; ++j) one.h[j] = 0x3F80;   // bf16 1.0
    #pragma unroll
    for (int ks = 0; ks < 2; ++ks) {
      short8 va[2];
      #pragma unroll
      for (int et = 0; et < 2; ++et)
        va[et] = *(const short8*)(Vb + (16 * et + l15) * 144 + ks * 64 + g * 16);
      #pragma unroll
      for (int mt = 0; mt < 4; ++mt) {
        o_[0][mt] = __builtin_amdgcn_mfma_f32_16x16x32_bf16(va[0], pvb[mt][ks], o_[0][mt], 0, 0, 0);
        o_[1][mt] = __builtin_amdgcn_mfma_f32_16x16x32_bf16(va[1], pvb[mt][ks], o_[1][mt], 0, 0, 0);
        d_[mt]    = __builtin_amdgcn_mfma_f32_16x16x32_bf16(one.s8, pvb[mt][ks], d_[mt], 0, 0, 0);
      }
    }
  }
  __syncthreads();   // all waves done reading planes/Vt -> region becomes outb

  // O^T tile: row e = 16et+4g+r, col m = 16mt+l15; d rows all identical
  float (*outb)[132] = (float (*)[132])smem;
  #pragma unroll
  for (int mt = 0; mt < 4; ++mt) {
    const int m = 16 * mt + l15;
    if (m < S_) {
      const float inv = 1.f / d_[mt][0];
      #pragma unroll
      for (int et = 0; et < 2; ++et)
        #pragma unroll
        for (int r = 0; r < 4; ++r)
          outb[m][(16 * et + 4 * g + r) * 4 + wv] = o_[et][mt][r] * inv;
    }
  }
  __syncthreads();

  // ---- coalesced output with un-roll(+3)
  for (int idx = tid; idx < S_ * 32; idx += 256) {
    const int pp = idx >> 5, c4 = idx & 31;
    const int ppx = pp / 7, ppy = pp % 7;
    const int fi = (wh * 7 + ppx + 3) % H_;
    const int fj = (ww * 7 + ppy + 3) % W_;
    float4 val = *(const float4*)&outb[pp][c4 * 4];
    ((float4*)(out + (((size_t)b * H_ + fi) * W_ + fj) * 128))[c4] = val;
  }
}

extern "C" void kernel_launch(void* const* d_in, const int* in_sizes, int n_in,
                              void* d_out, int out_size, void* d_ws, size_t ws_size,
                              hipStream_t stream) {
  const float* x   = (const float*)d_in[0];
  const float* v   = (const float*)d_in[1];
  const float* Wqk = (const float*)d_in[2];
  const float* bqk = (const float*)d_in[3];
  const float* pos = (const float*)d_in[4];
  float* out = (float*)d_out;
  unsigned short* Wb = (unsigned short*)d_ws;   // 65536 B (do NOT use ws beyond this)

  hipLaunchKernelGGL(wprep, dim3(32), dim3(256), 0, stream, Wqk, Wb);
  hipLaunchKernelGGL(swin_fused, dim3(B_ * WT * WT), dim3(256), 0, stream,
                     x, v, bqk, pos, Wb, out);
}

// Round 15
// 163.046 us; speedup vs baseline: 1.3321x; 1.0170x over previous
//
#include <hip/hip_runtime.h>
#include <hip/hip_bf16.h>
#include <math.h>

#define NH_ 4
#define S_  49
#define B_  16
#define H_  112
#define W_  112
#define WT  16

typedef __attribute__((ext_vector_type(8))) short short8;
typedef __attribute__((ext_vector_type(4))) float f32x4;

__device__ __forceinline__ unsigned short f2bf(float f) {
  union { __hip_bfloat16 h; unsigned short u; } c;
  c.h = __float2bfloat16(f);
  return c.u;
}
__device__ __forceinline__ short8 cvt8(float4 a, float4 b) {
  union { short8 s; unsigned short u[8]; } r;
  r.u[0] = f2bf(a.x); r.u[1] = f2bf(a.y); r.u[2] = f2bf(a.z); r.u[3] = f2bf(a.w);
  r.u[4] = f2bf(b.x); r.u[5] = f2bf(b.y); r.u[6] = f2bf(b.z); r.u[7] = f2bf(b.w);
  return r.s;
}

// ---- prep: Wqk f32 [256][128] -> bf16 in workspace (first 64 KB of ws ONLY)
__global__ void wprep(const float* __restrict__ Wqk, unsigned short* __restrict__ Wb) {
  int i = (blockIdx.x * blockDim.x + threadIdx.x) * 4;
  float4 w = *(const float4*)(Wqk + i);
  ushort4 o; o.x = f2bf(w.x); o.y = f2bf(w.y); o.z = f2bf(w.z); o.w = f2bf(w.w);
  *(ushort4*)(Wb + i) = o;
}

// LDS map (bytes):
//   0     : v_raw f32 [50][128] = 25600 (DMA-staged, linear) -> then qk planes
//           8 x 4112 = 32896 -> then outb f32 [49][132]
//   32896 : Vt_p bf16 4 x [32 e][72 slots] = 18432 (k-permuted, p>=49 zeroed)
//   51328 : posl f32 [169] = 676
//   52032 : x_raw f32 [50][128] = 25600 (DMA-staged, 16B-chunk src-swizzled: slot j
//           of row p holds global chunk j^(p&7))          total 77632 -> 2 blocks/CU
#define PSTR   4112
#define SM_VT  32896
#define SM_POS 51328
#define SM_X   52032
#define SM_TOT 77632

__global__ __launch_bounds__(256, 2) void swin_fused(
    const float* __restrict__ xg, const float* __restrict__ vg,
    const float* __restrict__ bqk, const float* __restrict__ pos,
    const unsigned short* __restrict__ Wb, float* __restrict__ out)
{
  __shared__ __align__(1024) char smem[SM_TOT];
  float* posl = (float*)(smem + SM_POS);

  const int tid  = threadIdx.x;
  const int lane = tid & 63;
  const int g    = lane >> 4, l15 = lane & 15;
  const int wv   = tid >> 6;
  const int blk  = blockIdx.x;
  const int ww   = blk % WT, wh = (blk / WT) % WT, b = blk / (WT * WT);

  // ---- DMA stage: v -> [0..25600) linear ; x -> SM_X with src-chunk swizzle.
  //   issue k covers 1 KB = 2 pixel rows; lane = (p-2k)*32 + chunk.
  for (int k = wv; k < 25; k += 4) {
    const int p   = 2 * k + (lane >> 5);
    const int pcl = p < S_ ? p : S_ - 1;          // clamp; rows >=49 never read
    const int ppx = pcl / 7, ppy = pcl % 7;
    const int gi = (wh * 7 + ppx + 4) % H_;
    const int gj = (ww * 7 + ppy + 4) % W_;
    const size_t pixo = (((size_t)b * H_ + gi) * W_ + gj) * 128;
    {
      const float* src = vg + pixo + (lane & 31) * 4;
      __builtin_amdgcn_global_load_lds(
          (const __attribute__((address_space(1))) void*)src,
          (__attribute__((address_space(3))) void*)(smem + k * 1024),
          16, 0, 0);
    }
    {
      const int j  = lane & 31;
      const int js = j ^ (pcl & 7);               // pre-swizzled source chunk
      const float* src = xg + pixo + js * 4;
      __builtin_amdgcn_global_load_lds(
          (const __attribute__((address_space(1))) void*)src,
          (__attribute__((address_space(3))) void*)(smem + SM_X + k * 1024),
          16, 0, 0);
    }
  }
  if (tid < 169) posl[tid] = pos[tid];
  __syncthreads();   // DMA drained (syncthreads waits vmcnt(0)) — v_raw/x_raw ready

  // ---- Vt_p build from v_raw (LDS): pixel t at permuted k-slot.
  //   t = 16b1b0 + 4gg + rr -> k = 32b1 + 8gg + 4b0 + rr
  #pragma unroll
  for (int it = 0; it < 2; ++it) {
    const int idx = tid + it * 256;
    const int e = idx & 31, p4 = idx >> 5;
    const int kbase = 32 * (p4 >> 3) + 8 * (p4 & 3) + 4 * ((p4 >> 2) & 1);
    union { ushort4 v4; unsigned short u[4]; } hv[4];
    #pragma unroll
    for (int j = 0; j < 4; ++j) {
      const int p = p4 * 4 + j;
      float4 vv = {0.f, 0.f, 0.f, 0.f};
      if (p < S_) vv = *(const float4*)(smem + p * 512 + e * 16);
      hv[0].u[j] = f2bf(vv.x); hv[1].u[j] = f2bf(vv.y);
      hv[2].u[j] = f2bf(vv.z); hv[3].u[j] = f2bf(vv.w);
    }
    #pragma unroll
    for (int h = 0; h < 4; ++h)
      *(ushort4*)(smem + SM_VT + h * 4608 + e * 144 + kbase * 2) = hv[h].v4;
  }

  // ---- A-frags from x_raw (LDS, swizzled chunks)
  short8 af[4];
  {
    const int prow = 16 * wv + l15;
    const int pc = prow < S_ ? prow : S_ - 1;
    const char* xr = smem + SM_X + pc * 512;
    const int key = pc & 7;
    #pragma unroll
    for (int kk = 0; kk < 4; ++kk) {
      const int c0 = kk * 8 + g * 2;
      float4 a0 = *(const float4*)(xr + ((c0    ) ^ key) * 16);
      float4 a1 = *(const float4*)(xr + ((c0 + 1) ^ key) * 16);
      af[kk] = cvt8(a0, a1);
    }
  }
  __syncthreads();   // all v_raw/x_raw reads done -> region 0.. becomes qk planes

  // ---- projection (r9 structure): 64 MFMA, plane writes
  {
    const int mbase = 16 * wv + 4 * g;
    #pragma unroll
    for (int n16 = 0; n16 < 16; ++n16) {
      const int n = n16 * 16 + l15;
      f32x4 acc = {0.f, 0.f, 0.f, 0.f};
      #pragma unroll
      for (int kk = 0; kk < 4; ++kk) {
        short8 bfr = *(const short8*)(Wb + n * 128 + kk * 32 + g * 8);
        acc = __builtin_amdgcn_mfma_f32_16x16x32_bf16(af[kk], bfr, acc, 0, 0, 0);
      }
      const float bias = bqk[n];
      char* plane = smem + ((((n >> 1) & 3) * 2 + (n & 1))) * PSTR;   // 2h+s
      const int eoff = (n >> 3) * 2;
      #pragma unroll
      for (int r = 0; r < 4; ++r)
        *(unsigned short*)(plane + (mbase + r) * 64 + eoff) = f2bf(acc[r] + bias);
    }
  }
  __syncthreads();   // qk planes + Vt + posl ready

  // ---- attention: wave = head; SWAPPED QK^T (r9, verified)
  const bool maskR = (wh == WT - 1), maskC = (ww == WT - 1);
  const char* qpl = smem + (wv * 2 + 0) * PSTR;
  const char* kpl = smem + (wv * 2 + 1) * PSTR;
  short8 qf[4], kf[4];
  #pragma unroll
  for (int t4 = 0; t4 < 4; ++t4) {
    qf[t4] = *(const short8*)(qpl + (16 * t4 + l15) * 64 + g * 16);
    kf[t4] = *(const short8*)(kpl + (16 * t4 + l15) * 64 + g * 16);
  }

  f32x4 st[4][4];   // st[nt][mt]: D[row=t=16nt+4g+r][col=m=16mt+l15]
  #pragma unroll
  for (int nt = 0; nt < 4; ++nt)
    #pragma unroll
    for (int mt = 0; mt < 4; ++mt) {
      f32x4 z = {0.f, 0.f, 0.f, 0.f};
      st[nt][mt] = __builtin_amdgcn_mfma_f32_16x16x32_bf16(kf[nt], qf[mt], z, 0, 0, 0);
    }

  int tix[4][4]; bool txg[4][4], tyg[4][4], tvl[4][4];
  #pragma unroll
  for (int nt = 0; nt < 4; ++nt)
    #pragma unroll
    for (int r = 0; r < 4; ++r) {
      const int t = 16 * nt + 4 * g + r;
      const int tx = t / 7, ty = t - 7 * tx;
      tix[nt][r] = tx * 13 + ty;
      txg[nt][r] = (tx >= 4); tyg[nt][r] = (ty >= 4);
      tvl[nt][r] = (t < S_);
    }

  if (maskR || maskC) {      // uniform branch: ~12% of blocks
    #pragma unroll
    for (int mt = 0; mt < 4; ++mt) {
      const int m = 16 * mt + l15;
      const int mc = m < S_ ? m : S_ - 1;
      const int px = mc / 7, py = mc - 7 * px;
      const bool pxg = (px >= 4), pyg = (py >= 4);
      #pragma unroll
      for (int nt = 0; nt < 4; ++nt)
        #pragma unroll
        for (int r = 0; r < 4; ++r) {
          if ((maskR && (pxg != txg[nt][r])) || (maskC && (pyg != tyg[nt][r])))
            st[nt][mt][r] = -INFINITY;
        }
    }
  }

  const float scale = 0.17677669529663687f;   // 1/sqrt(32)
  short8 pvb[4][2];   // [mt][ks]; elem j = j2*4+r <-> t = 16(2ks+j2)+4g+r
  #pragma unroll
  for (int mt = 0; mt < 4; ++mt) {
    const int m = 16 * mt + l15;
    const int mc = m < S_ ? m : S_ - 1;
    const int px = mc / 7, py = mc - 7 * px;
    const int pofs = 84 - px * 13 - py;
    union { short8 s8; unsigned short h[8]; } pk[2];
    #pragma unroll
    for (int nt = 0; nt < 4; ++nt)
      #pragma unroll
      for (int r = 0; r < 4; ++r) {
        float s = st[nt][mt][r] * scale + posl[tix[nt][r] + pofs];
        float e = tvl[nt][r] ? __expf(s) : 0.f;
        pk[nt >> 1].h[(nt & 1) * 4 + r] = f2bf(e);
      }
    pvb[mt][0] = pk[0].s8;
    pvb[mt][1] = pk[1].s8;
  }

  // PV: O^T = V^T . P^T ; denominators via ones-operand MFMA
  f32x4 o_[2][4], d_[4];
  #pragma unroll
  for (int mt = 0; mt < 4; ++mt) {
    o_[0][mt] = (f32x4){0.f, 0.f, 0.f, 0.f};
    o_[1][mt] = (f32x4){0.f, 0.f, 0.f, 0.f};
    d_[mt]    = (f32x4){0.f, 0.f, 0.f, 0.f};
  }
  {
    const char* Vb = smem + SM_VT + wv * 4608;
    union { short8 s8; unsigned short h[8]; } one;
    #pragma unroll
    for (int j = 0; j < 8; ++j) one.h[j] = 0x3F80;   // bf16 1.0
    #pragma unroll
    for (int ks = 0; ks < 2; ++ks) {
      short8 va[2];
      #pragma unroll
      for (int et = 0; et < 2; ++et)
        va[et] = *(const short8*)(Vb + (16 * et + l15) * 144 + ks * 64 + g * 16);
      #pragma unroll
      for (int mt = 0; mt < 4; ++mt) {
        o_[0][mt] = __builtin_amdgcn_mfma_f32_16x16x32_bf16(va[0], pvb[mt][ks], o_[0][mt], 0, 0, 0);
        o_[1][mt] = __builtin_amdgcn_mfma_f32_16x16x32_bf16(va[1], pvb[mt][ks], o_[1][mt], 0, 0, 0);
        d_[mt]    = __builtin_amdgcn_mfma_f32_16x16x32_bf16(one.s8, pvb[mt][ks], d_[mt], 0, 0, 0);
      }
    }
  }
  __syncthreads();   // all waves done reading planes/Vt -> region becomes outb

  float (*outb)[132] = (float (*)[132])smem;
  #pragma unroll
  for (int mt = 0; mt < 4; ++mt) {
    const int m = 16 * mt + l15;
    if (m < S_) {
      const float inv = 1.f / d_[mt][0];
      #pragma unroll
      for (int et = 0; et < 2; ++et)
        #pragma unroll
        for (int r = 0; r < 4; ++r)
          outb[m][(16 * et + 4 * g + r) * 4 + wv] = o_[et][mt][r] * inv;
    }
  }
  __syncthreads();

  // ---- coalesced output with un-roll(+3)
  for (int idx = tid; idx < S_ * 32; idx += 256) {
    const int pp = idx >> 5, c4 = idx & 31;
    const int ppx = pp / 7, ppy = pp % 7;
    const int fi = (wh * 7 + ppx + 3) % H_;
    const int fj = (ww * 7 + ppy + 3) % W_;
    float4 val = *(const float4*)&outb[pp][c4 * 4];
    ((float4*)(out + (((size_t)b * H_ + fi) * W_ + fj) * 128))[c4] = val;
  }
}

extern "C" void kernel_launch(void* const* d_in, const int* in_sizes, int n_in,
                              void* d_out, int out_size, void* d_ws, size_t ws_size,
                              hipStream_t stream) {
  const float* x   = (const float*)d_in[0];
  const float* v   = (const float*)d_in[1];
  const float* Wqk = (const float*)d_in[2];
  const float* bqk = (const float*)d_in[3];
  const float* pos = (const float*)d_in[4];
  float* out = (float*)d_out;
  unsigned short* Wb = (unsigned short*)d_ws;   // 65536 B (do NOT use ws beyond this)

  hipLaunchKernelGGL(wprep, dim3(32), dim3(256), 0, stream, Wqk, Wb);
  hipLaunchKernelGGL(swin_fused, dim3(B_ * WT * WT), dim3(256), 0, stream,
                     x, v, bqk, pos, Wb, out);
}